// Round 11
// baseline (300.292 us; speedup 1.0000x reference)
//
#include <hip/hip_runtime.h>
#include <hip/hip_fp16.h>

// RoIAlign3D: features (B=2, C=256, 64,64,64) f32, proposals (B=2, N=512, 6) f32
// out: (B*N, C, 7, 7, 7) f32
//
// kernel1: bucket 3584 (roi,iz) entries per batch by z0=floor(gz) into CSR +
//   32 B record {x1p,sx,y1p,sy, wz,out_off,-,-}.
// kernel2: block = (z0, slice-PAIR). Stage planes z0,z0+1 of TWO channel
//   slices as z-pair f16 slots: slot64(y,x) = {pk(h[x],h[x+1])@z0,
//   pk(h[x],h[x+1])@z0+1} (8 B). Per point per channel: ONE ds_read2_b64
//   (rows y0,y0+1) -> all 8 corners. Geometry computed once per entry for
//   both channels (VALU -33%, records halved).
//   CHUNK=1 re-reads each plane 2x, but block (z0,pi)->XCD pi%8 for all z0,
//   so the re-read hits the same XCD's L2 one round later.
// Coords in [0,63): floor<=62, +1<=63 -> no clamping; slot x=63 never read.

#define B_      2
#define C_      256
#define N_      512
#define NENT    (N_ * 7)
#define SP      66                  // slots per row (64 used + 2 pad)
#define PLANE_P (64 * SP)           // 4224 uint2 slots per slice
#define THREADS 1024
#define GROUPS  20                  // 20*49 = 980 active lanes
#define REC_F_BASE 128
#define WS_NEEDED ((size_t)REC_F_BASE * 4 + (size_t)B_ * NENT * 8 * 4)

typedef _Float16 h2v __attribute__((ext_vector_type(2)));

__device__ __forceinline__ float gcoord(float lo, float hi, int i) {
    return lo + (hi - lo) * (1.0f / 6.0f) * (float)i;
}

__device__ __forceinline__ uint32_t pkrtz(float a, float b) {
    auto h = __builtin_amdgcn_cvt_pkrtz(a, b);
    return __builtin_bit_cast(uint32_t, h);
}

// (1-wx)*v.lo + wx*v.hi with f32 accumulation
__device__ __forceinline__ float xlerp(uint32_t pkv, uint32_t pkw) {
#if __has_builtin(__builtin_amdgcn_fdot2)
    return __builtin_amdgcn_fdot2(__builtin_bit_cast(h2v, pkv),
                                  __builtin_bit_cast(h2v, pkw), 0.0f, false);
#else
    h2v v = __builtin_bit_cast(h2v, pkv);
    h2v w = __builtin_bit_cast(h2v, pkw);
    return (float)v[0] * (float)w[0] + (float)v[1] * (float)w[1];
#endif
}

// ---- kernel 1: bucket + per-entry record ----
__global__ __launch_bounds__(256) void bucket_kernel(
    const float* __restrict__ props, int* __restrict__ wsi, float* __restrict__ wsf)
{
    int b = blockIdx.x;
    __shared__ int counts[63];
    __shared__ int starts[64];
    __shared__ int cursors[63];
    int tid = threadIdx.x;
    if (tid < 63) counts[tid] = 0;
    __syncthreads();
    for (int e = tid; e < NENT; e += 256) {
        int n = e / 7, iz = e - n * 7;
        const float* pr = props + (size_t)(b * N_ + n) * 6;
        float gz = gcoord(pr[2], pr[5], iz);
        int z0 = min(max((int)gz, 0), 62);
        atomicAdd(&counts[z0], 1);
    }
    __syncthreads();
    if (tid == 0) {
        int s = 0;
        for (int k = 0; k < 63; ++k) { starts[k] = s; s += counts[k]; }
        starts[63] = s;
    }
    __syncthreads();
    if (tid < 63) cursors[tid] = starts[tid];
    __syncthreads();
    for (int e = tid; e < NENT; e += 256) {
        int n = e / 7, iz = e - n * 7;
        const float* pr = props + (size_t)(b * N_ + n) * 6;
        float x1p = pr[0], y1p = pr[1], z1p = pr[2];
        float x2p = pr[3], y2p = pr[4], z2p = pr[5];
        float gz = gcoord(z1p, z2p, iz);
        int z0 = min(max((int)gz, 0), 62);
        float wz = gz - (float)z0;
        int pos = atomicAdd(&cursors[z0], 1);
        int off = (b * N_ + n) * (C_ * 343) + iz * 49;
        float* r = wsf + REC_F_BASE + (size_t)(b * NENT + pos) * 8;
        r[0] = x1p; r[1] = (x2p - x1p) * (1.0f / 6.0f);
        r[2] = y1p; r[3] = (y2p - y1p) * (1.0f / 6.0f);
        r[4] = wz;  r[5] = __int_as_float(off);
        r[6] = 0.0f; r[7] = 0.0f;
    }
    if (tid < 64) wsi[b * 64 + tid] = starts[tid];
}

// ---- kernel 2: block = (z0, slice-pair); z-pair slots, 2 channels/entry ----
__global__ __launch_bounds__(THREADS, 8) void roialign3d_zpair_kernel(
    const float* __restrict__ feat,
    const int* __restrict__ wsi,
    const float* __restrict__ wsf,
    float* __restrict__ out)
{
    __shared__ __align__(16) uint2 pk2[2 * PLANE_P];   // 67584 B

    int bid = blockIdx.x;
    int pi  = bid & 255;           // slice-pair -> XCD pi%8 every round
    int z0  = bid >> 8;            // 0..62
    int b   = pi >> 7;
    int c0  = (pi & 127) << 1;     // channels c0, c0+1
    int tid = threadIdx.x;

    int base = wsi[b * 64 + z0];
    int end  = wsi[b * 64 + z0 + 1];
    if (base == end) return;       // empty bucket: skip staging entirely

    const float* vol0 = feat + ((size_t)((b << 8) + c0) << 18) + ((size_t)z0 << 12);
    const float* vol1 = vol0 + (1 << 18);

    // ---- stage loads: 2 slices x planes z0,z0+1 (64 KB in flight) ----
    float4 a0 = *(const float4*)(vol0 + (tid << 2));
    float4 a1 = *(const float4*)(vol0 + 4096 + (tid << 2));
    float4 b0 = *(const float4*)(vol1 + (tid << 2));
    float4 b1 = *(const float4*)(vol1 + 4096 + (tid << 2));

    // dense lane map + record prefetch (behind plane loads)
    int g = tid / 49;
    int p = tid - g * 49;
    int iy = p / 7;
    float fx = (float)(p - iy * 7);
    float fy = (float)iy;
    const float4* recs = (const float4*)(wsf + REC_F_BASE);
    const int rbase = b * NENT;
    int myEnd = (g < GROUPS) ? end : base;
    int e = base + g;
    float4 rA, rB, rAn, rBn;
    if (e < myEnd) {
        rA = recs[(size_t)(rbase + e) * 2];
        rB = recs[(size_t)(rbase + e) * 2 + 1];
        if (e + GROUPS < myEnd) {
            rAn = recs[(size_t)(rbase + e + GROUPS) * 2];
            rBn = recs[(size_t)(rbase + e + GROUPS) * 2 + 1];
        }
    }

    // ---- convert + write: slot64(y,x) = {xpair@z0, xpair@z0+1} ----
    {
        int swb = (tid >> 4) * SP + ((tid & 15) << 2);   // uint2 slot index
        float a0n = __shfl_down(a0.x, 1);
        float a1n = __shfl_down(a1.x, 1);
        float b0n = __shfl_down(b0.x, 1);
        float b1n = __shfl_down(b1.x, 1);
        uint2* d0 = &pk2[swb];
        uint2* d1 = &pk2[PLANE_P + swb];
        d0[0] = make_uint2(pkrtz(a0.x, a0.y), pkrtz(a1.x, a1.y));
        d0[1] = make_uint2(pkrtz(a0.y, a0.z), pkrtz(a1.y, a1.z));
        d0[2] = make_uint2(pkrtz(a0.z, a0.w), pkrtz(a1.z, a1.w));
        d0[3] = make_uint2(pkrtz(a0.w, a0n),  pkrtz(a1.w, a1n));
        d1[0] = make_uint2(pkrtz(b0.x, b0.y), pkrtz(b1.x, b1.y));
        d1[1] = make_uint2(pkrtz(b0.y, b0.z), pkrtz(b1.y, b1.z));
        d1[2] = make_uint2(pkrtz(b0.z, b0.w), pkrtz(b1.z, b1.w));
        d1[3] = make_uint2(pkrtz(b0.w, b0n),  pkrtz(b1.w, b1n));
    }
    __syncthreads();

    // ---- entry loop: geometry once, two channels per entry ----
    float* outc = out + (size_t)c0 * 343;
    while (e < myEnd) {
        float gx = fmaf(rA.y, fx, rA.x);
        float gy = fmaf(rA.w, fy, rA.z);
        int x0 = (int)gx, y0 = (int)gy;
        float wx = __builtin_amdgcn_fractf(gx);
        float wy = __builtin_amdgcn_fractf(gy);
        uint32_t pw = pkrtz(1.0f - wx, wx);
        float wz = rB.x;
        int offc = __float_as_int(rB.y);
        int sl = y0 * SP + x0;
        uint2 qa0 = pk2[sl],           qa1 = pk2[sl + SP];          // slice 0
        uint2 qb0 = pk2[PLANE_P + sl], qb1 = pk2[PLANE_P + sl + SP]; // slice 1

        // rotate record pipeline; prefetch e+2*GROUPS
        float4 tA = rAn, tB = rBn;
        int e2 = e + 2 * GROUPS;
        if (e2 < myEnd) {
            rAn = recs[(size_t)(rbase + e2) * 2];
            rBn = recs[(size_t)(rbase + e2) * 2 + 1];
        }

        // channel c0
        {
            float c00 = xlerp(qa0.x, pw);   // z0 , y0
            float c10 = xlerp(qa0.y, pw);   // z0+1, y0
            float c01 = xlerp(qa1.x, pw);   // z0 , y0+1
            float c11 = xlerp(qa1.y, pw);   // z0+1, y0+1
            float d0 = fmaf(c01 - c00, wy, c00);
            float d1 = fmaf(c11 - c10, wy, c10);
            outc[offc + p] = fmaf(d1 - d0, wz, d0);
        }
        // channel c0+1
        {
            float c00 = xlerp(qb0.x, pw);
            float c10 = xlerp(qb0.y, pw);
            float c01 = xlerp(qb1.x, pw);
            float c11 = xlerp(qb1.y, pw);
            float d0 = fmaf(c01 - c00, wy, c00);
            float d1 = fmaf(c11 - c10, wy, c10);
            outc[offc + 343 + p] = fmaf(d1 - d0, wz, d0);
        }

        e += GROUPS; rA = tA; rB = tB;
    }
}

// ---- fallback (ws too small): round-1 kernel, known correct ----
__global__ __launch_bounds__(128) void roialign3d_fallback(
    const float* __restrict__ feat, const float* __restrict__ props,
    float* __restrict__ out)
{
    int bid = blockIdx.x;
    int xcd = bid & 7;
    int j   = bid >> 3;
    int s   = xcd + ((j >> 9) << 3);
    int n   = j & 511;
    int b   = s >> 8;
    int c   = s & 255;
    const float* prop = props + ((size_t)(b * N_ + n)) * 6;
    float x1p = prop[0], y1p = prop[1], z1p = prop[2];
    float x2p = prop[3], y2p = prop[4], z2p = prop[5];
    float sx = (x2p - x1p) * (1.0f / 6.0f);
    float sy = (y2p - y1p) * (1.0f / 6.0f);
    float sz = (z2p - z1p) * (1.0f / 6.0f);
    const float* vol = feat + (size_t)s * (64 * 64 * 64);
    float* o = out + ((size_t)(b * N_ + n) * C_ + c) * 343;
    for (int p = threadIdx.x; p < 343; p += 128) {
        int iz = p / 49, r = p - iz * 49, iy = r / 7, ix = r - iy * 7;
        float gx = x1p + sx * ix, gy = y1p + sy * iy, gz = z1p + sz * iz;
        int x0 = (int)gx, y0 = (int)gy, z0 = (int)gz;
        float wx = gx - x0, wy = gy - y0, wz = gz - z0;
        int x1 = min(x0 + 1, 63), y1 = min(y0 + 1, 63), z1 = min(z0 + 1, 63);
        const float* p00 = vol + ((z0 * 64 + y0) << 6);
        const float* p01 = vol + ((z0 * 64 + y1) << 6);
        const float* p10 = vol + ((z1 * 64 + y0) << 6);
        const float* p11 = vol + ((z1 * 64 + y1) << 6);
        float c00 = p00[x0] + (p00[x1] - p00[x0]) * wx;
        float c01 = p01[x0] + (p01[x1] - p01[x0]) * wx;
        float c10 = p10[x0] + (p10[x1] - p10[x0]) * wx;
        float c11 = p11[x0] + (p11[x1] - p11[x0]) * wx;
        float d0 = c00 + (c01 - c00) * wy;
        float d1 = c10 + (c11 - c10) * wy;
        o[p] = d0 + (d1 - d0) * wz;
    }
}

extern "C" void kernel_launch(void* const* d_in, const int* in_sizes, int n_in,
                              void* d_out, int out_size, void* d_ws, size_t ws_size,
                              hipStream_t stream) {
    const float* feat  = (const float*)d_in[0];
    const float* props = (const float*)d_in[1];
    float* out = (float*)d_out;

    if (ws_size < WS_NEEDED) {
        roialign3d_fallback<<<B_ * C_ * N_, 128, 0, stream>>>(feat, props, out);
        return;
    }
    int*   wsi = (int*)d_ws;
    float* wsf = (float*)d_ws;
    bucket_kernel<<<B_, 256, 0, stream>>>(props, wsi, wsf);
    roialign3d_zpair_kernel<<<63 * 256, THREADS, 0, stream>>>(feat, wsi, wsf, out);
}